// Round 1
// 85.107 us; speedup vs baseline: 1.0295x; 1.0295x over previous
//
#include <hip/hip_runtime.h>

// Fully fused SMFNet. N=8192, D=64. chord mask = diag + wrapped superdiag, so
// W@V == V_new[i] = a_i*V[i] + b_i*V[(i+1)%N]. One block = 16 output rows;
// it computes V0 for 20 context rows, V1 for 17, out for 16 (neighbor chain).
// R3 (this round): VALU-issue diet.
//  - 3 of 4 matmuls (g0, f00, f01) have A = X (global, wave-uniform rows):
//    broadcast now comes from the SCALAR pipe (readfirstlane'd row index ->
//    uniform s_load_dwordx4), deleting ~960 v_readlane per wave. Bit-identical
//    fma order to R2.
//  - weights staged in contiguous PAIRS (g0+g1, f00+f01): barriers 7 -> 4,
//    no stage/compute serialization inside a pair. LDS 42.9 KB, still 2 blk/CU.
//  - V1s trimmed to the 17 rows actually consumed.

#define NROWS 8192
#define BROWS 16   // output rows per block
#define RPW 5      // rows per wave (4 waves * 5 = 20 context rows)

__device__ __forceinline__ float rl(float v, int lane) {
  return __int_as_float(__builtin_amdgcn_readlane(__float_as_int(v), lane));
}

// full-wave (64 lane) sum; result uniform across lanes. DPP row_ror 1/2/4/8
// reduces within each 16-lane row (VALU pipe), readlane combines the 4 rows.
__device__ __forceinline__ float wave_sum(float x) {
  x += __int_as_float(__builtin_amdgcn_update_dpp(0, __float_as_int(x), 0x121, 0xF, 0xF, false));
  x += __int_as_float(__builtin_amdgcn_update_dpp(0, __float_as_int(x), 0x122, 0xF, 0xF, false));
  x += __int_as_float(__builtin_amdgcn_update_dpp(0, __float_as_int(x), 0x124, 0xF, 0xF, false));
  x += __int_as_float(__builtin_amdgcn_update_dpp(0, __float_as_int(x), 0x128, 0xF, 0xF, false));
  float a0 = rl(x, 0), a1 = rl(x, 16), a2 = rl(x, 32), a3 = rl(x, 48);
  return (a0 + a1) + (a2 + a3);
}

// stage TWO consecutive 64x64 row-major matrices into k-chunked LDS:
// Wq[m][kb][j] = {W_m[j][4kb..4kb+3]}  (same layout as R2, two at a time)
__device__ __forceinline__ void stageW2(float4 (*Wq)[16][65],
                                        const float* __restrict__ W, int tid) {
  const float4* ws = (const float4*)W;
#pragma unroll
  for (int p = 0; p < 8; ++p) {
    int idx = p * 256 + tid;              // 0..2047, coalesced global float4
    int rem = idx & 1023;
    Wq[idx >> 10][rem & 15][rem >> 4] = ws[idx];
  }
}

// acc[r] = relu(sum_k X[growu[r]][k]*W[lane][k] + bias).
// growu[] is readfirstlane'd (SGPR) -> the A loads are wave-uniform and go to
// the scalar/SMEM pipe; no per-element v_readlane. fma order identical to R2.
template <int R>
__device__ __forceinline__ void mm64_s(const float4 (*Wq)[65], int lane,
                                       const float* __restrict__ X,
                                       const int* growu, float bias, float* acc) {
#pragma unroll
  for (int r = 0; r < R; ++r) acc[r] = bias;
#pragma unroll 4
  for (int kb = 0; kb < 16; ++kb) {
    float4 w4 = Wq[kb][lane];             // ds_read_b128, lane-contiguous
#pragma unroll
    for (int r = 0; r < R; ++r) {
      float4 xq = *(const float4*)(X + (growu[r] << 6) + (kb << 2));  // s_load
      acc[r] = fmaf(xq.x, w4.x, acc[r]);
      acc[r] = fmaf(xq.y, w4.y, acc[r]);
      acc[r] = fmaf(xq.z, w4.z, acc[r]);
      acc[r] = fmaf(xq.w, w4.w, acc[r]);
    }
  }
#pragma unroll
  for (int r = 0; r < R; ++r) acc[r] = fmaxf(acc[r], 0.0f);
}

// A-operand broadcast from registers via v_readlane (for reg-resident A = H)
template <int R>
__device__ __forceinline__ void mm64_rl(const float4 (*Wq)[65], int lane,
                                        const float* src, float bias, float* acc) {
#pragma unroll
  for (int r = 0; r < R; ++r) acc[r] = bias;
#pragma unroll 4
  for (int kb = 0; kb < 16; ++kb) {
    float4 w4 = Wq[kb][lane];
#pragma unroll
    for (int r = 0; r < R; ++r) {
      acc[r] = fmaf(rl(src[r], 4 * kb + 0), w4.x, acc[r]);
      acc[r] = fmaf(rl(src[r], 4 * kb + 1), w4.y, acc[r]);
      acc[r] = fmaf(rl(src[r], 4 * kb + 2), w4.z, acc[r]);
      acc[r] = fmaf(rl(src[r], 4 * kb + 3), w4.w, acc[r]);
    }
  }
#pragma unroll
  for (int r = 0; r < R; ++r) acc[r] = fmaxf(acc[r], 0.0f);
}

__global__ __launch_bounds__(256, 2) void fused_smfnet(
    const float* __restrict__ X, const float* __restrict__ g_w,
    const float* __restrict__ g_b, const float* __restrict__ f0_w,
    const float* __restrict__ f0_b, const float* __restrict__ fL_w,
    const float* __restrict__ fL_b, float* __restrict__ out)
{
  __shared__ float4 Wq[2][16][65];  // 33.3 KB, two matrices per stage
  __shared__ float V0s[20][65];     // neighbor access for chord combine
  __shared__ float V1s[17][65];     // rows 0..16 are the only ones consumed

  const int tid  = threadIdx.x;
  const int lane = tid & 63;
  const int wv   = tid >> 6;                 // wave id 0..3
  const int r0   = blockIdx.x * BROWS;

  stageW2(Wq, g_w, tid);                     // g0 + g1
  float hb  = g_b[lane];
  float vb  = g_b[64 + lane];

  int growu[RPW];                            // wave-uniform (SGPR) row indices
#pragma unroll
  for (int r = 0; r < RPW; ++r) {
    int L = wv * RPW + r;
    growu[r] = __builtin_amdgcn_readfirstlane((r0 + L) & (NROWS - 1));
  }
  __syncthreads();                           // g0,g1 staged

  float h[RPW];
  mm64_s<RPW>(Wq[0], lane, X, growu, hb, h); // H = relu(X @ g0^T + b0)

  float v0[RPW];
  mm64_rl<RPW>(Wq[1], lane, h, vb, v0);      // V0 = relu(H @ g1^T + b1)
#pragma unroll
  for (int r = 0; r < RPW; ++r) V0s[wv * RPW + r][lane] = v0[r];

  __syncthreads();                           // V0s visible; Wq free
  stageW2(Wq, f0_w, tid);                    // f00 + f01
  __syncthreads();

  float tb0 = f0_b[lane];
  float t[RPW];
  mm64_s<RPW>(Wq[0], lane, X, growu, tb0, t); // T0 = relu(X @ f00^T + b)

  float v1[RPW];
#pragma unroll
  for (int r = 0; r < RPW; ++r) {
    int L = wv * RPW + r;
    if (L <= 16) {                           // wave-uniform predicate
      int g   = growu[r];
      int gp1 = (g + 1) & (NROWS - 1);
      float pa = wave_sum(t[r] * fL_w[g * 64 + lane]);
      float pb = wave_sum(t[r] * fL_w[gp1 * 64 + lane]);
      float a  = fmaxf(pa + fL_b[g], 0.0f);
      float b  = fmaxf(pb + fL_b[gp1], 0.0f);
      v1[r] = a * v0[r] + b * V0s[L + 1][lane];
      V1s[L][lane] = v1[r];
    }
  }

  __syncthreads();                           // V1s visible; Wq[1] still f01
  float tb1 = f0_b[64 + lane];
  mm64_s<RPW>(Wq[1], lane, X, growu, tb1, t); // T1 = relu(X @ f01^T + b)

  const float* fw1 = fL_w + NROWS * 64;
  const float* fb1 = fL_b + NROWS;
#pragma unroll
  for (int r = 0; r < RPW; ++r) {
    int L = wv * RPW + r;
    if (L <= 15) {
      int g   = growu[r];
      int gp1 = (g + 1) & (NROWS - 1);
      float pa = wave_sum(t[r] * fw1[g * 64 + lane]);
      float pb = wave_sum(t[r] * fw1[gp1 * 64 + lane]);
      float a  = fmaxf(pa + fb1[g], 0.0f);
      float b  = fmaxf(pb + fb1[gp1], 0.0f);
      out[g * 64 + lane] = a * v1[r] + b * V1s[L + 1][lane];
    }
  }
}

extern "C" void kernel_launch(void* const* d_in, const int* in_sizes, int n_in,
                              void* d_out, int out_size, void* d_ws, size_t ws_size,
                              hipStream_t stream) {
  const float* X    = (const float*)d_in[0];  // [8192,64]
  const float* g_w  = (const float*)d_in[1];  // [2,64,64]
  const float* g_b  = (const float*)d_in[2];  // [2,64]
  const float* f0_w = (const float*)d_in[3];  // [2,64,64]
  const float* f0_b = (const float*)d_in[4];  // [2,64]
  const float* fL_w = (const float*)d_in[5];  // [2,8192,64]
  const float* fL_b = (const float*)d_in[6];  // [2,8192]
  float* out = (float*)d_out;                 // [8192,64] fp32

  fused_smfnet<<<dim3(NROWS / BROWS), dim3(256), 0, stream>>>(
      X, g_w, g_b, f0_w, f0_b, fL_w, fL_b, out);
}